// Round 10
// baseline (5128.858 us; speedup 1.0000x reference)
//
#include <hip/hip_runtime.h>
#include <stdint.h>

typedef unsigned short u16;
typedef float f4 __attribute__((ext_vector_type(4)));
typedef float f16v __attribute__((ext_vector_type(16)));
typedef short s8v __attribute__((ext_vector_type(8)));

static __device__ __forceinline__ float bf2f(u16 u){ return __uint_as_float(((unsigned)u)<<16); }
static __device__ __forceinline__ u16 f2bf(float f){
  unsigned u = __float_as_uint(f);
  unsigned r = u + 0x7fffu + ((u>>16)&1u);
  return (u16)(r>>16);
}

// ---------------- workspace layout (bytes) ----------------
#define WS_H    0ull            // h: [4][64][65536] fp32
#define WS_T    67108864ull     // t: same
#define WS_WDH  134217728ull    // dual hi frags (10*73728 u16)
#define WS_WDL  135692288ull
#define WS_W2H  137166848ull    // w2 hi frags (10*36864 u16)
#define WS_W2L  137904128ull
#define WS_W0T  138641408ull    // [6ci][9tap][64co] fp32 (conv0)
#define WS_WFH  138655232ull    // fin hi frags (18432 u16)
#define WS_WFL  138692096ull    // fin lo frags (18432 u16)
#define WS_PAR  138728960ull    // fp32 params

// par float offsets
#define S0 0
#define T0 8
#define S1 16
#define T1 656
#define S2 1296
#define T2 1936
#define SF 2576
#define TF 2640
#define MK 2704
#define CB 3332

// output element offsets — FLOAT32
#define O_PRED   0ull
#define O_PREDF  786432ull
#define O_MASKF  1572864ull
#define O_ATTN   8126464ull
#define O_PREDB  8388608ull
#define O_MASKB  9175040ull
#define O_OMA    15728640ull

// ---------------- params ----------------
__global__ void k_prep(const float* g0,const float* b0,const float* m0,const float* v0,
                       const float* g1,const float* b1,const float* m1,const float* v1,
                       const float* g2,const float* b2,const float* m2,const float* v2,
                       const float* gf,const float* bf_,const float* mf,const float* vf,
                       const float* mk,const float* cb, float* par){
  for (int i = threadIdx.x; i < 640; i += 256){
    if (i < 6){ float s = g0[i]/sqrtf(v0[i]+1e-5f); par[S0+i]=s; par[T0+i]=b0[i]-m0[i]*s; }
    { float s = g1[i]/sqrtf(v1[i]+1e-5f); par[S1+i]=s; par[T1+i]=b1[i]-m1[i]*s; }
    { float s = g2[i]/sqrtf(v2[i]+1e-5f); par[S2+i]=s; par[T2+i]=b2[i]-m2[i]*s; }
    if (i < 64){ float s = gf[i]/sqrtf(vf[i]+1e-5f); par[SF+i]=s; par[TF+i]=bf_[i]-mf[i]*s; }
    if (i < 625) par[MK+i] = mk[i];
    if (i < 25)  par[CB+i] = cb[i];
  }
}

// ---------------- conv0 weights: [ci][tap][co] fp32 ----------------
__global__ void k_wx2(const float* w0, float* w0t){
  int e = blockIdx.x*256 + threadIdx.x;
  if (e < 3456){
    int o = e & 63, r = e >> 6;
    int tap = r % 9, c = r / 9;
    w0t[e] = w0[(o*6+c)*9 + tap];
  }
}

// ---------------- MFMA weight fragment streams for 32x32x16 (hi/lo bf16x2) ----------------
// dual/w2: frag[b][tf][kc][cog][lane][8]: co=cog*32+(l&31); ci=h*32+kc*16+(l>>5)*8+j; tf=h*NT+tap
// fin:     frag[tf][kc][lane][8] (NCOG=1), tf = h*9+tap in [0,18); co=(l&31)<25 else 0
__global__ void k_wxm(const float* w11, const float* w12, const float* w2, const float* wf,
                      u16* wdH, u16* wdL, u16* w2H, u16* w2L, u16* wfH, u16* wfL){
  int e = blockIdx.x*256 + threadIdx.x;
  if (e < 737280){
    int j = e & 7, l = (e>>3) & 63, cog = (e>>9) & 1, kc = (e>>10) & 1;
    int idx2 = e >> 11;
    int tf = idx2 % 36, b = idx2 / 36;
    int tap = tf % 18, h = tf / 18;
    int co = cog*32 + (l & 31);
    int ci = h*32 + kc*16 + (l>>5)*8 + j;
    float w = (tap < 9) ? w11[((b*64+co)*64+ci)*9 + tap]
                        : w12[((b*64+co)*64+ci)*9 + (tap-9)];
    u16 hi = f2bf(w);
    wdH[e] = hi; wdL[e] = f2bf(w - bf2f(hi));
  } else if (e < 1105920){
    int e2 = e - 737280;
    int j = e2 & 7, l = (e2>>3) & 63, cog = (e2>>9) & 1, kc = (e2>>10) & 1;
    int idx2 = e2 >> 11;
    int tf = idx2 % 18, b = idx2 / 18;
    int tap = tf % 9, h = tf / 9;
    int co = cog*32 + (l & 31);
    int ci = h*32 + kc*16 + (l>>5)*8 + j;
    float w = w2[((b*64+co)*64+ci)*9 + tap];
    u16 hi = f2bf(w);
    w2H[e2] = hi; w2L[e2] = f2bf(w - bf2f(hi));
  } else if (e < 1124352){
    int e3 = e - 1105920;               // [0, 18432)
    int j = e3 & 7, l = (e3>>3) & 63, kc = (e3>>9) & 1, tf = e3 >> 10;  // tf in [0,18)
    int tap = tf % 9, h = tf / 9;
    int co = l & 31;
    int ci = h*32 + kc*16 + (l>>5)*8 + j;
    float w = (co < 25) ? wf[(co*64+ci)*9 + tap] : 0.f;
    u16 hi = f2bf(w);
    wfH[e3] = hi; wfL[e3] = f2bf(w - bf2f(hi));
  }
}

// ---------------- unified MFMA conv (32x32x16, bf16x2 3-term, swizzled LDS) ----------------
// Block 256 = 4 waves; tile 32x8 px. NCOG=2: wave=(cog=wv&1, rows rh*4..+3), 64 co.
// NCOG=1 (fin): wave = rows wv*2..+1, 32 co (25 valid). A-prefetch double-buffered.
// OUTMODE 0: store; 1: residual add; 2: +bias, softmax25 -> dmask planar.
template<int NT,int TAPSET,int OUTMODE,int NCOG>
__global__ __launch_bounds__(256,2) void k_mc(
    const float* __restrict__ in, float* __restrict__ outb,
    const u16* __restrict__ wH, const u16* __restrict__ wL,
    const float* __restrict__ sc_, const float* __restrict__ tc_,
    const float* __restrict__ cbv, float* __restrict__ dmask){
  constexpr int RPW = 2*NCOG;
  __shared__ __align__(16) u16 ldsH[432*32];
  __shared__ __align__(16) u16 ldsL[432*32];
  __shared__ float lsc[64], ltc[64];
  const int t = threadIdx.x;
  if (t < 64){ lsc[t] = sc_[t]; ltc[t] = tc_[t]; }
  const int img = blockIdx.z, ox = blockIdx.x*32, oy = blockIdx.y*8;
  const int lane = t & 63, wv = t >> 6;
  const int cog = (NCOG==2) ? (wv & 1) : 0;
  const int rh  = (NCOG==2) ? (wv >> 1) : wv;
  const int xcol = lane & 31, g = lane >> 5;
  f16v acc[RPW];
  #pragma unroll
  for (int r=0;r<RPW;r++) acc[r] = (f16v)(0.f);
  const s8v* wH8 = (const s8v*)wH;
  const s8v* wL8 = (const s8v*)wL;

  #pragma unroll 1
  for (int h = 0; h < 2; ++h){
    __syncthreads();
    // stage: bn+relu+hi/lo split, swizzled LDS write
    for (int idx = t; idx < 1728; idx += 256){
      int oct = idx / 432, px = idx % 432;
      int pr = px / 36, pc = px % 36;
      int gy = oy + pr - 2, gx = ox + pc - 2;
      int cb = h*32 + oct*8;
      s8v vh = {0,0,0,0,0,0,0,0}, vl = {0,0,0,0,0,0,0,0};
      if ((unsigned)gy < 256u && (unsigned)gx < 256u){
        const float* ip = in + (((size_t)(img*64 + cb))<<16) + gy*256 + gx;
        #pragma unroll
        for (int k=0;k<8;k++){
          float v = fmaxf(ip[(size_t)k<<16]*lsc[cb+k] + ltc[cb+k], 0.f);
          u16 hi = f2bf(v);
          vh[k] = (short)hi;
          vl[k] = (short)f2bf(v - bf2f(hi));
        }
      }
      int ad = (px*64 + oct*16) ^ ((px&7)<<4);
      *(s8v*)((char*)ldsH + ad) = vh;
      *(s8v*)((char*)ldsL + ad) = vl;
    }
    __syncthreads();

    // A-prefetch pipeline over m = tap*2 + kc
    s8v ah0, al0, ah1, al1;
    {
      size_t o = (size_t)((h*NT*2)*NCOG + cog)*64 + lane;
      ah0 = wH8[o]; al0 = wL8[o];
    }
    #pragma unroll
    for (int m = 0; m < 2*NT; ++m){
      const int tap = m >> 1, kc = m & 1;
      int dy, dx;
      if (TAPSET==0){
        if (tap < 9){ dy = tap/3 - 1; dx = tap%3 - 1; }
        else { int dd = tap-9; dy = 2*(dd/3 - 1); dx = 2*(dd%3 - 1); }
      } else { dy = tap/3 - 1; dx = tap%3 - 1; }
      if (m+1 < 2*NT){
        size_t o = (size_t)(((h*NT + ((m+1)>>1))*2 + ((m+1)&1))*NCOG + cog)*64 + lane;
        if ((m&1)==0){ ah1 = wH8[o]; al1 = wL8[o]; }
        else         { ah0 = wH8[o]; al0 = wL8[o]; }
      }
      const s8v Ah = ((m&1)==0) ? ah0 : ah1;
      const s8v Al = ((m&1)==0) ? al0 : al1;
      #pragma unroll
      for (int r = 0; r < RPW; ++r){
        int row = rh*RPW + r;
        int px = (row + dy + 2)*36 + (xcol + dx + 2);
        int ad = (px*64 + kc*32 + g*16) ^ ((px&7)<<4);
        s8v xh = *(const s8v*)((const char*)ldsH + ad);
        s8v xl = *(const s8v*)((const char*)ldsL + ad);
        acc[r] = __builtin_amdgcn_mfma_f32_32x32x16_bf16(Ah, xh, acc[r], 0,0,0);
        acc[r] = __builtin_amdgcn_mfma_f32_32x32x16_bf16(Al, xh, acc[r], 0,0,0);
        acc[r] = __builtin_amdgcn_mfma_f32_32x32x16_bf16(Ah, xl, acc[r], 0,0,0);
      }
    }
  }

  // D layout (m74/m101): col = lane&31 = px-x; row = (j&3)+8*(j>>2)+4*g = co%32
  if (OUTMODE != 2){
    #pragma unroll
    for (int r=0;r<RPW;r++){
      int y = oy + rh*RPW + r;
      int x = ox + xcol;
      #pragma unroll
      for (int j=0;j<16;j++){
        int co = cog*32 + (j&3) + 8*(j>>2) + 4*g;
        size_t o = (((size_t)(img*64 + co))<<16) + (size_t)(y*256 + x);
        if (OUTMODE==0) outb[o] = acc[r][j];
        else            outb[o] += acc[r][j];
      }
    }
  } else {
    #pragma unroll
    for (int r=0;r<RPW;r++){
      int y = oy + rh*RPW + r;
      int x = ox + xcol;
      float lg[16];
      float mx = -3.4e38f;
      #pragma unroll
      for (int j=0;j<16;j++){
        int co = (j&3) + 8*(j>>2) + 4*g;
        float v = acc[r][j] + ((co < 25) ? cbv[co] : 0.f);
        lg[j] = v;
        if (co < 25) mx = fmaxf(mx, v);
      }
      mx = fmaxf(mx, __shfl_xor(mx, 32));
      float s = 0.f;
      #pragma unroll
      for (int j=0;j<16;j++){
        int co = (j&3) + 8*(j>>2) + 4*g;
        float e = (co < 25) ? __expf(lg[j]-mx) : 0.f;
        lg[j] = e; s += e;
      }
      s += __shfl_xor(s, 32);
      float inv = 1.f/s;
      #pragma unroll
      for (int j=0;j<16;j++){
        int co = (j&3) + 8*(j>>2) + 4*g;
        if (co < 25)
          dmask[(((size_t)(img*25+co))<<16) + (size_t)(y*256 + x)] = lg[j]*inv;
      }
    }
  }
}

// ---------------- conv0 (VALU, 6ci): tile 16x8, LDS staged ----------------
__global__ __launch_bounds__(256) void k_conv0(
    const float* __restrict__ in, float* __restrict__ outb,
    const float* __restrict__ wt, const float* __restrict__ sc_,
    const float* __restrict__ tc_){
  __shared__ float lin[4*12*20];
  __shared__ float lw[4*9*64];
  __shared__ float lsc[8], ltc[8];
  const int t = threadIdx.x;
  const int img = blockIdx.z;
  const int ox = blockIdx.x*16, oy = blockIdx.y*8;
  if (t < 6){ lsc[t] = sc_[t]; ltc[t] = tc_[t]; }
  const int wv = t>>6, lane = t&63;
  const int row = lane>>4, col = lane&15;
  const int co0 = wv*16;
  const int pb0 = (row+2)*20 + col + 2;
  const int pb1 = pb0 + 80;
  f4 a0[4], a1[4];
  #pragma unroll
  for (int q=0;q<4;q++){ a0[q] = f4{0.f,0.f,0.f,0.f}; a1[q] = f4{0.f,0.f,0.f,0.f}; }

  #pragma unroll 1
  for (int c0=0; c0<6; c0+=4){
    const int cc = (6 - c0 < 4) ? (6 - c0) : 4;
    __syncthreads();
    for (int idx=t; idx<cc*240; idx+=256){
      int c = idx/240, rr = (idx/20)%12, xx = idx%20;
      int gy = oy + rr - 2, gx = ox + xx - 2;
      float v = 0.f;
      if ((unsigned)gy < 256u && (unsigned)gx < 256u)
        v = in[(size_t)(img*6 + c0 + c)*65536 + gy*256 + gx]*lsc[c0+c] + ltc[c0+c];
      lin[idx] = v;
    }
    {
      const f4* ws4 = (const f4*)(wt + (size_t)c0*576);
      f4* lw4 = (f4*)lw;
      for (int idx=t; idx<cc*144; idx+=256) lw4[idx] = ws4[idx];
    }
    __syncthreads();
    #pragma unroll 1
    for (int c=0; c<cc; c++){
      const float* lpc = lin + c*240;
      const float* lwc = lw + c*576 + co0;
      #pragma unroll
      for (int tap=0; tap<9; tap++){
        int dy = tap/3 - 1, dx = tap%3 - 1;
        float v0 = lpc[pb0 + dy*20 + dx];
        float v1 = lpc[pb1 + dy*20 + dx];
        const f4* wp = (const f4*)(lwc + tap*64);
        #pragma unroll
        for (int q=0;q<4;q++){
          f4 w = wp[q];
          a0[q] += v0*w;
          a1[q] += v1*w;
        }
      }
    }
  }

  size_t p0 = (size_t)((oy+row)*256 + ox + col);
  size_t base = (size_t)(img*64 + co0)*65536;
  #pragma unroll
  for (int q=0;q<4;q++)
    #pragma unroll
    for (int j=0;j<4;j++){
      outb[base + (size_t)(q*4+j)*65536 + p0]        = a0[q][j];
      outb[base + (size_t)(q*4+j)*65536 + p0 + 1024] = a1[q][j];
    }
}

// ---------------- seg / pred / attn / blend ----------------
__global__ __launch_bounds__(256) void k_blend(const float* __restrict__ msk,
    const float* __restrict__ imf, const float* __restrict__ imb,
    const float* __restrict__ ones_in, const float* __restrict__ par,
    float* __restrict__ out){
  int bid = blockIdx.x;
  int swz = (bid & 7)*128 + (bid >> 3);
  int img = swz >> 8, y = swz & 255, x = threadIdx.x;
  int p = y*256 + x;
  int aofs[25]; unsigned vm = 0u;
  #pragma unroll
  for (int tap=0; tap<25; tap++){
    int dy = tap/5-2, dx = tap%5-2, yy = y+dy, xx = x+dx;
    bool okb = ((unsigned)yy < 256u) && ((unsigned)xx < 256u);
    aofs[tap] = okb ? (yy*256+xx) : 0;
    vm |= (okb ? 1u : 0u) << tap;
  }
  float sff[25], sfb[25];
  #pragma unroll
  for (int i=0;i<25;i++){ sff[i]=0.f; sfb[i]=0.f; }
  #pragma unroll 1
  for (int k=0;k<25;k++){
    const float* mF = msk + O_MASKF + ((size_t)(img*25+k)<<16);
    const float* mB = msk + O_MASKB + ((size_t)(img*25+k)<<16);
    #pragma unroll
    for (int tap=0; tap<25; tap++){
      float mkv = par[MK + k*25 + tap];
      float vF = (vm >> tap & 1u) ? mF[aofs[tap]] : 0.f;
      float vB = (vm >> tap & 1u) ? mB[aofs[tap]] : 0.f;
      sff[tap] += mkv*vF;
      sfb[tap] += mkv*vB;
    }
  }
  float segf = 0.f, segb = 0.f;
  float pf[3] = {0.f,0.f,0.f}, pb[3] = {0.f,0.f,0.f};
  size_t ib = ((size_t)(img*6))<<16;
  #pragma unroll
  for (int tap=0; tap<25; tap++){
    if (vm >> tap & 1u){
      float one = ones_in[((size_t)img<<16) + (size_t)aofs[tap]];
      segf += one*sff[tap]; segb += one*sfb[tap];
      #pragma unroll
      for (int c=0;c<3;c++){
        pf[c] += imf[ib + ((size_t)(3+c)<<16) + (size_t)aofs[tap]] * sff[tap];
        pb[c] += imb[ib + ((size_t)(3+c)<<16) + (size_t)aofs[tap]] * sfb[tap];
      }
    }
  }
  float attn = (segf + 1e-5f)/(segf + segb + 2e-5f);
  float na = 1.f - attn;
  #pragma unroll
  for (int c=0;c<3;c++){
    size_t off = (size_t)(img*3+c)*65536 + p;
    out[O_PRED  + off] = attn*pf[c] + na*pb[c];
    out[O_PREDF + off] = pf[c];
    out[O_PREDB + off] = pb[c];
  }
  size_t oa = ((size_t)img<<16) + (size_t)p;
  out[O_ATTN + oa] = attn;
  out[O_OMA  + oa] = na;
}

// ---------------- launch ----------------
extern "C" void kernel_launch(void* const* d_in, const int* in_sizes, int n_in,
                              void* d_out, int out_size, void* d_ws, size_t ws_size,
                              hipStream_t stream){
  (void)in_sizes; (void)n_in; (void)out_size; (void)ws_size;
  char* ws = (char*)d_ws;
  float* h   = (float*)(ws + WS_H);
  float* tb  = (float*)(ws + WS_T);
  u16*  wdH  = (u16*)(ws + WS_WDH);
  u16*  wdL  = (u16*)(ws + WS_WDL);
  u16*  w2H  = (u16*)(ws + WS_W2H);
  u16*  w2L  = (u16*)(ws + WS_W2L);
  float* w0t = (float*)(ws + WS_W0T);
  u16*  wfH  = (u16*)(ws + WS_WFH);
  u16*  wfL  = (u16*)(ws + WS_WFL);
  float* par = (float*)(ws + WS_PAR);
  float* out = (float*)d_out;

  k_prep<<<1,256,0,stream>>>((const float*)d_in[4],(const float*)d_in[5],(const float*)d_in[6],(const float*)d_in[7],
                             (const float*)d_in[9],(const float*)d_in[10],(const float*)d_in[11],(const float*)d_in[12],
                             (const float*)d_in[15],(const float*)d_in[16],(const float*)d_in[17],(const float*)d_in[18],
                             (const float*)d_in[20],(const float*)d_in[21],(const float*)d_in[22],(const float*)d_in[23],
                             (const float*)d_in[3],(const float*)d_in[25], par);
  k_wx2<<<14,256,0,stream>>>((const float*)d_in[8], w0t);
  k_wxm<<<4392,256,0,stream>>>((const float*)d_in[13],(const float*)d_in[14],(const float*)d_in[19],
                               (const float*)d_in[24],
                               wdH, wdL, w2H, w2L, wfH, wfL);

  dim3 g0(16,32,4);   // conv0: 16x8 tiles
  dim3 gm(8,32,4);    // mfma convs: 32x8 tiles
  for (int dir=0; dir<2; dir++){
    const float* im = (const float*)d_in[dir];
    float* dmask = out + (dir ? O_MASKB : O_MASKF);
    k_conv0<<<g0,256,0,stream>>>(im, h, w0t, par+S0, par+T0);
    for (int b=0;b<10;b++){
      k_mc<18,0,0,2><<<gm,256,0,stream>>>(h, tb, wdH + (size_t)b*73728, wdL + (size_t)b*73728,
                                          par + S1 + b*64, par + T1 + b*64, nullptr, nullptr);
      k_mc<9,1,1,2><<<gm,256,0,stream>>>(tb, h, w2H + (size_t)b*36864, w2L + (size_t)b*36864,
                                         par + S2 + b*64, par + T2 + b*64, nullptr, nullptr);
    }
    k_mc<9,1,2,1><<<gm,256,0,stream>>>(h, nullptr, wfH, wfL,
                                       par + SF, par + TF, par + CB, dmask);
  }
  k_blend<<<1024,256,0,stream>>>(out, (const float*)d_in[0], (const float*)d_in[1],
                                 (const float*)d_in[2], par, out);
}

// Round 11
// 4357.639 us; speedup vs baseline: 1.1770x; 1.1770x over previous
//
#include <hip/hip_runtime.h>
#include <stdint.h>

typedef unsigned short u16;
typedef float f4 __attribute__((ext_vector_type(4)));
typedef float f16v __attribute__((ext_vector_type(16)));
typedef short s8v __attribute__((ext_vector_type(8)));

static __device__ __forceinline__ float bf2f(u16 u){ return __uint_as_float(((unsigned)u)<<16); }
static __device__ __forceinline__ u16 f2bf(float f){
  unsigned u = __float_as_uint(f);
  unsigned r = u + 0x7fffu + ((u>>16)&1u);
  return (u16)(r>>16);
}

// ---------------- workspace layout (bytes) ----------------
#define WS_H    0ull            // h: [4][64][65536] fp32 = 67,108,864
#define WS_TH   67108864ull     // t hi: [4][64][65536] u16 = 33,554,432 (pre-activated bn2+relu)
#define WS_TL   100663296ull    // t lo
#define WS_WDH  134217728ull    // dual hi frags (10*73728 u16)
#define WS_WDL  135692288ull
#define WS_W2H  137166848ull    // w2 hi frags (10*36864 u16)
#define WS_W2L  137904128ull
#define WS_W0T  138641408ull    // [6ci][9tap][64co] fp32 (conv0)
#define WS_WFH  138655232ull    // fin hi frags (18432 u16)
#define WS_WFL  138692096ull    // fin lo frags (18432 u16)
#define WS_PAR  138728960ull    // fp32 params

// par float offsets
#define S0 0
#define T0 8
#define S1 16
#define T1 656
#define S2 1296
#define T2 1936
#define SF 2576
#define TF 2640
#define MK 2704
#define CB 3332

// output element offsets — FLOAT32
#define O_PRED   0ull
#define O_PREDF  786432ull
#define O_MASKF  1572864ull
#define O_ATTN   8126464ull
#define O_PREDB  8388608ull
#define O_MASKB  9175040ull
#define O_OMA    15728640ull

// ---------------- params ----------------
__global__ void k_prep(const float* g0,const float* b0,const float* m0,const float* v0,
                       const float* g1,const float* b1,const float* m1,const float* v1,
                       const float* g2,const float* b2,const float* m2,const float* v2,
                       const float* gf,const float* bf_,const float* mf,const float* vf,
                       const float* mk,const float* cb, float* par){
  for (int i = threadIdx.x; i < 640; i += 256){
    if (i < 6){ float s = g0[i]/sqrtf(v0[i]+1e-5f); par[S0+i]=s; par[T0+i]=b0[i]-m0[i]*s; }
    { float s = g1[i]/sqrtf(v1[i]+1e-5f); par[S1+i]=s; par[T1+i]=b1[i]-m1[i]*s; }
    { float s = g2[i]/sqrtf(v2[i]+1e-5f); par[S2+i]=s; par[T2+i]=b2[i]-m2[i]*s; }
    if (i < 64){ float s = gf[i]/sqrtf(vf[i]+1e-5f); par[SF+i]=s; par[TF+i]=bf_[i]-mf[i]*s; }
    if (i < 625) par[MK+i] = mk[i];
    if (i < 25)  par[CB+i] = cb[i];
  }
}

// ---------------- conv0 weights: [ci][tap][co] fp32 ----------------
__global__ void k_wx2(const float* w0, float* w0t){
  int e = blockIdx.x*256 + threadIdx.x;
  if (e < 3456){
    int o = e & 63, r = e >> 6;
    int tap = r % 9, c = r / 9;
    w0t[e] = w0[(o*6+c)*9 + tap];
  }
}

// ---------------- MFMA weight fragment streams for 32x32x16 (hi/lo bf16x2) ----------------
// dual/w2: frag[b][tf][kc][cog][lane][8]: co=cog*32+(l&31); ci=h*32+kc*16+(l>>5)*8+j; tf=h*NT+tap
// fin:     frag[tf][kc][lane][8] (NCOG=1), tf = h*9+tap in [0,18); co=(l&31)<25 else 0
__global__ void k_wxm(const float* w11, const float* w12, const float* w2, const float* wf,
                      u16* wdH, u16* wdL, u16* w2H, u16* w2L, u16* wfH, u16* wfL){
  int e = blockIdx.x*256 + threadIdx.x;
  if (e < 737280){
    int j = e & 7, l = (e>>3) & 63, cog = (e>>9) & 1, kc = (e>>10) & 1;
    int idx2 = e >> 11;
    int tf = idx2 % 36, b = idx2 / 36;
    int tap = tf % 18, h = tf / 18;
    int co = cog*32 + (l & 31);
    int ci = h*32 + kc*16 + (l>>5)*8 + j;
    float w = (tap < 9) ? w11[((b*64+co)*64+ci)*9 + tap]
                        : w12[((b*64+co)*64+ci)*9 + (tap-9)];
    u16 hi = f2bf(w);
    wdH[e] = hi; wdL[e] = f2bf(w - bf2f(hi));
  } else if (e < 1105920){
    int e2 = e - 737280;
    int j = e2 & 7, l = (e2>>3) & 63, cog = (e2>>9) & 1, kc = (e2>>10) & 1;
    int idx2 = e2 >> 11;
    int tf = idx2 % 18, b = idx2 / 18;
    int tap = tf % 9, h = tf / 9;
    int co = cog*32 + (l & 31);
    int ci = h*32 + kc*16 + (l>>5)*8 + j;
    float w = w2[((b*64+co)*64+ci)*9 + tap];
    u16 hi = f2bf(w);
    w2H[e2] = hi; w2L[e2] = f2bf(w - bf2f(hi));
  } else if (e < 1124352){
    int e3 = e - 1105920;               // [0, 18432)
    int j = e3 & 7, l = (e3>>3) & 63, kc = (e3>>9) & 1, tf = e3 >> 10;  // tf in [0,18)
    int tap = tf % 9, h = tf / 9;
    int co = l & 31;
    int ci = h*32 + kc*16 + (l>>5)*8 + j;
    float w = (co < 25) ? wf[(co*64+ci)*9 + tap] : 0.f;
    u16 hi = f2bf(w);
    wfH[e3] = hi; wfL[e3] = f2bf(w - bf2f(hi));
  }
}

// ---------------- unified MFMA conv (32x32x16, bf16x2 3-term, swizzled LDS) ----------------
// Block 256 = 4 waves; tile 32x8 px. Wave wv: rows {wv*2, wv*2+1}, ALL cogs (NCOG).
// Per (tap,kc): load 2*NCOG A-frags inline, 2 B-reads per row feed 3*NCOG MFMAs.
// INMODE 0: fp32 input + bn+relu+split at stage. 1: pre-activated bf16 H/L planar copy.
// OUTMODE 0: fp32 store; 1: fp32 residual add; 2: +bias softmax25 -> dmask;
//         3: fused bn(osc,otc)+relu+split -> bf16 H/L planar (outH/outL).
template<int NT,int TAPSET,int OUTMODE,int NCOG,int INMODE>
__global__ __launch_bounds__(256,2) void k_mc(
    const void* __restrict__ in, const u16* __restrict__ inL,
    float* __restrict__ outb, u16* __restrict__ outH, u16* __restrict__ outL,
    const u16* __restrict__ wH, const u16* __restrict__ wL,
    const float* __restrict__ sc_, const float* __restrict__ tc_,
    const float* __restrict__ osc_, const float* __restrict__ otc_,
    const float* __restrict__ cbv, float* __restrict__ dmask){
  __shared__ __align__(16) u16 ldsH[432*32];
  __shared__ __align__(16) u16 ldsL[432*32];
  __shared__ float lsc[64], ltc[64];
  __shared__ float losc[64], lotc[64];
  const int t = threadIdx.x;
  if (INMODE==0 && t < 64){ lsc[t] = sc_[t]; ltc[t] = tc_[t]; }
  if (OUTMODE==3 && t >= 64 && t < 128){ losc[t-64] = osc_[t-64]; lotc[t-64] = otc_[t-64]; }
  const int img = blockIdx.z, ox = blockIdx.x*32, oy = blockIdx.y*8;
  const int lane = t & 63, wv = t >> 6;
  const int xcol = lane & 31, g = lane >> 5;
  f16v acc[NCOG][2];
  #pragma unroll
  for (int cg=0;cg<NCOG;cg++)
    #pragma unroll
    for (int r=0;r<2;r++) acc[cg][r] = (f16v)(0.f);
  const s8v* wH8 = (const s8v*)wH;
  const s8v* wL8 = (const s8v*)wL;

  #pragma unroll 1
  for (int h = 0; h < 2; ++h){
    __syncthreads();
    // stage 32 channels of half h into swizzled LDS (H and L planes)
    for (int idx = t; idx < 1728; idx += 256){
      int oct = idx / 432, px = idx % 432;
      int pr = px / 36, pc = px % 36;
      int gy = oy + pr - 2, gx = ox + pc - 2;
      int cb = h*32 + oct*8;
      s8v vh = {0,0,0,0,0,0,0,0}, vl = {0,0,0,0,0,0,0,0};
      if ((unsigned)gy < 256u && (unsigned)gx < 256u){
        size_t base = (((size_t)(img*64 + cb))<<16) + (size_t)(gy*256 + gx);
        if (INMODE==0){
          const float* ip = (const float*)in + base;
          #pragma unroll
          for (int k=0;k<8;k++){
            float v = fmaxf(ip[(size_t)k<<16]*lsc[cb+k] + ltc[cb+k], 0.f);
            u16 hi = f2bf(v);
            vh[k] = (short)hi;
            vl[k] = (short)f2bf(v - bf2f(hi));
          }
        } else {
          const u16* iph = (const u16*)in + base;
          const u16* ipl = inL + base;
          #pragma unroll
          for (int k=0;k<8;k++){
            vh[k] = (short)iph[(size_t)k<<16];
            vl[k] = (short)ipl[(size_t)k<<16];
          }
        }
      }
      int ad = (px*64 + oct*16) ^ ((px&7)<<4);
      *(s8v*)((char*)ldsH + ad) = vh;
      *(s8v*)((char*)ldsL + ad) = vl;
    }
    __syncthreads();

    #pragma unroll
    for (int tap = 0; tap < NT; ++tap){
      int dy, dx;
      if (TAPSET==0){
        if (tap < 9){ dy = tap/3 - 1; dx = tap%3 - 1; }
        else { int dd = tap-9; dy = 2*(dd/3 - 1); dx = 2*(dd%3 - 1); }
      } else { dy = tap/3 - 1; dx = tap%3 - 1; }
      const int tf = h*NT + tap;
      #pragma unroll
      for (int kc = 0; kc < 2; ++kc){
        s8v ah0, al0, ah1, al1;
        {
          size_t o = (size_t)((tf*2 + kc)*NCOG + 0)*64 + lane;
          ah0 = wH8[o]; al0 = wL8[o];
        }
        if (NCOG==2){
          size_t o = (size_t)((tf*2 + kc)*NCOG + 1)*64 + lane;
          ah1 = wH8[o]; al1 = wL8[o];
        }
        #pragma unroll
        for (int r = 0; r < 2; ++r){
          int px = (wv*2 + r + dy + 2)*36 + (xcol + dx + 2);
          int ad = (px*64 + kc*32 + g*16) ^ ((px&7)<<4);
          s8v xh = *(const s8v*)((const char*)ldsH + ad);
          s8v xl = *(const s8v*)((const char*)ldsL + ad);
          acc[0][r] = __builtin_amdgcn_mfma_f32_32x32x16_bf16(ah0, xh, acc[0][r], 0,0,0);
          if (NCOG==2) acc[1][r] = __builtin_amdgcn_mfma_f32_32x32x16_bf16(ah1, xh, acc[1][r], 0,0,0);
          acc[0][r] = __builtin_amdgcn_mfma_f32_32x32x16_bf16(al0, xh, acc[0][r], 0,0,0);
          if (NCOG==2) acc[1][r] = __builtin_amdgcn_mfma_f32_32x32x16_bf16(al1, xh, acc[1][r], 0,0,0);
          acc[0][r] = __builtin_amdgcn_mfma_f32_32x32x16_bf16(ah0, xl, acc[0][r], 0,0,0);
          if (NCOG==2) acc[1][r] = __builtin_amdgcn_mfma_f32_32x32x16_bf16(ah1, xl, acc[1][r], 0,0,0);
        }
      }
    }
  }

  // D layout (m74/m101): col = lane&31 = px-x; row = (j&3)+8*(j>>2)+4*g = co%32
  if (OUTMODE==0 || OUTMODE==1){
    #pragma unroll
    for (int r=0;r<2;r++){
      int y = oy + wv*2 + r;
      int x = ox + xcol;
      #pragma unroll
      for (int cg=0;cg<NCOG;cg++){
        #pragma unroll
        for (int j=0;j<16;j++){
          int co = cg*32 + (j&3) + 8*(j>>2) + 4*g;
          size_t o = (((size_t)(img*64 + co))<<16) + (size_t)(y*256 + x);
          if (OUTMODE==0) outb[o] = acc[cg][r][j];
          else            outb[o] += acc[cg][r][j];
        }
      }
    }
  } else if (OUTMODE==3){
    __syncthreads();   // ensure losc/lotc visible (written by threads 64..127 at entry)
    #pragma unroll
    for (int r=0;r<2;r++){
      int y = oy + wv*2 + r;
      int x = ox + xcol;
      #pragma unroll
      for (int cg=0;cg<NCOG;cg++){
        #pragma unroll
        for (int j=0;j<16;j++){
          int co = cg*32 + (j&3) + 8*(j>>2) + 4*g;
          float v = fmaxf(acc[cg][r][j]*losc[co] + lotc[co], 0.f);
          u16 hi = f2bf(v);
          u16 lo = f2bf(v - bf2f(hi));
          size_t o = (((size_t)(img*64 + co))<<16) + (size_t)(y*256 + x);
          outH[o] = hi;
          outL[o] = lo;
        }
      }
    }
  } else {
    #pragma unroll
    for (int r=0;r<2;r++){
      int y = oy + wv*2 + r;
      int x = ox + xcol;
      float lg[16];
      float mx = -3.4e38f;
      #pragma unroll
      for (int j=0;j<16;j++){
        int co = (j&3) + 8*(j>>2) + 4*g;
        float v = acc[0][r][j] + ((co < 25) ? cbv[co] : 0.f);
        lg[j] = v;
        if (co < 25) mx = fmaxf(mx, v);
      }
      mx = fmaxf(mx, __shfl_xor(mx, 32));
      float s = 0.f;
      #pragma unroll
      for (int j=0;j<16;j++){
        int co = (j&3) + 8*(j>>2) + 4*g;
        float e = (co < 25) ? __expf(lg[j]-mx) : 0.f;
        lg[j] = e; s += e;
      }
      s += __shfl_xor(s, 32);
      float inv = 1.f/s;
      #pragma unroll
      for (int j=0;j<16;j++){
        int co = (j&3) + 8*(j>>2) + 4*g;
        if (co < 25)
          dmask[(((size_t)(img*25+co))<<16) + (size_t)(y*256 + x)] = lg[j]*inv;
      }
    }
  }
}

// ---------------- conv0 (VALU, 6ci): tile 16x8, LDS staged ----------------
__global__ __launch_bounds__(256) void k_conv0(
    const float* __restrict__ in, float* __restrict__ outb,
    const float* __restrict__ wt, const float* __restrict__ sc_,
    const float* __restrict__ tc_){
  __shared__ float lin[4*12*20];
  __shared__ float lw[4*9*64];
  __shared__ float lsc[8], ltc[8];
  const int t = threadIdx.x;
  const int img = blockIdx.z;
  const int ox = blockIdx.x*16, oy = blockIdx.y*8;
  if (t < 6){ lsc[t] = sc_[t]; ltc[t] = tc_[t]; }
  const int wv = t>>6, lane = t&63;
  const int row = lane>>4, col = lane&15;
  const int co0 = wv*16;
  const int pb0 = (row+2)*20 + col + 2;
  const int pb1 = pb0 + 80;
  f4 a0[4], a1[4];
  #pragma unroll
  for (int q=0;q<4;q++){ a0[q] = f4{0.f,0.f,0.f,0.f}; a1[q] = f4{0.f,0.f,0.f,0.f}; }

  #pragma unroll 1
  for (int c0=0; c0<6; c0+=4){
    const int cc = (6 - c0 < 4) ? (6 - c0) : 4;
    __syncthreads();
    for (int idx=t; idx<cc*240; idx+=256){
      int c = idx/240, rr = (idx/20)%12, xx = idx%20;
      int gy = oy + rr - 2, gx = ox + xx - 2;
      float v = 0.f;
      if ((unsigned)gy < 256u && (unsigned)gx < 256u)
        v = in[(size_t)(img*6 + c0 + c)*65536 + gy*256 + gx]*lsc[c0+c] + ltc[c0+c];
      lin[idx] = v;
    }
    {
      const f4* ws4 = (const f4*)(wt + (size_t)c0*576);
      f4* lw4 = (f4*)lw;
      for (int idx=t; idx<cc*144; idx+=256) lw4[idx] = ws4[idx];
    }
    __syncthreads();
    #pragma unroll 1
    for (int c=0; c<cc; c++){
      const float* lpc = lin + c*240;
      const float* lwc = lw + c*576 + co0;
      #pragma unroll
      for (int tap=0; tap<9; tap++){
        int dy = tap/3 - 1, dx = tap%3 - 1;
        float v0 = lpc[pb0 + dy*20 + dx];
        float v1 = lpc[pb1 + dy*20 + dx];
        const f4* wp = (const f4*)(lwc + tap*64);
        #pragma unroll
        for (int q=0;q<4;q++){
          f4 w = wp[q];
          a0[q] += v0*w;
          a1[q] += v1*w;
        }
      }
    }
  }

  size_t p0 = (size_t)((oy+row)*256 + ox + col);
  size_t base = (size_t)(img*64 + co0)*65536;
  #pragma unroll
  for (int q=0;q<4;q++)
    #pragma unroll
    for (int j=0;j<4;j++){
      outb[base + (size_t)(q*4+j)*65536 + p0]        = a0[q][j];
      outb[base + (size_t)(q*4+j)*65536 + p0 + 1024] = a1[q][j];
    }
}

// ---------------- seg / pred / attn / blend ----------------
__global__ __launch_bounds__(256) void k_blend(const float* __restrict__ msk,
    const float* __restrict__ imf, const float* __restrict__ imb,
    const float* __restrict__ ones_in, const float* __restrict__ par,
    float* __restrict__ out){
  int bid = blockIdx.x;
  int swz = (bid & 7)*128 + (bid >> 3);
  int img = swz >> 8, y = swz & 255, x = threadIdx.x;
  int p = y*256 + x;
  int aofs[25]; unsigned vm = 0u;
  #pragma unroll
  for (int tap=0; tap<25; tap++){
    int dy = tap/5-2, dx = tap%5-2, yy = y+dy, xx = x+dx;
    bool okb = ((unsigned)yy < 256u) && ((unsigned)xx < 256u);
    aofs[tap] = okb ? (yy*256+xx) : 0;
    vm |= (okb ? 1u : 0u) << tap;
  }
  float sff[25], sfb[25];
  #pragma unroll
  for (int i=0;i<25;i++){ sff[i]=0.f; sfb[i]=0.f; }
  #pragma unroll 1
  for (int k=0;k<25;k++){
    const float* mF = msk + O_MASKF + ((size_t)(img*25+k)<<16);
    const float* mB = msk + O_MASKB + ((size_t)(img*25+k)<<16);
    #pragma unroll
    for (int tap=0; tap<25; tap++){
      float mkv = par[MK + k*25 + tap];
      float vF = (vm >> tap & 1u) ? mF[aofs[tap]] : 0.f;
      float vB = (vm >> tap & 1u) ? mB[aofs[tap]] : 0.f;
      sff[tap] += mkv*vF;
      sfb[tap] += mkv*vB;
    }
  }
  float segf = 0.f, segb = 0.f;
  float pf[3] = {0.f,0.f,0.f}, pb[3] = {0.f,0.f,0.f};
  size_t ib = ((size_t)(img*6))<<16;
  #pragma unroll
  for (int tap=0; tap<25; tap++){
    if (vm >> tap & 1u){
      float one = ones_in[((size_t)img<<16) + (size_t)aofs[tap]];
      segf += one*sff[tap]; segb += one*sfb[tap];
      #pragma unroll
      for (int c=0;c<3;c++){
        pf[c] += imf[ib + ((size_t)(3+c)<<16) + (size_t)aofs[tap]] * sff[tap];
        pb[c] += imb[ib + ((size_t)(3+c)<<16) + (size_t)aofs[tap]] * sfb[tap];
      }
    }
  }
  float attn = (segf + 1e-5f)/(segf + segb + 2e-5f);
  float na = 1.f - attn;
  #pragma unroll
  for (int c=0;c<3;c++){
    size_t off = (size_t)(img*3+c)*65536 + p;
    out[O_PRED  + off] = attn*pf[c] + na*pb[c];
    out[O_PREDF + off] = pf[c];
    out[O_PREDB + off] = pb[c];
  }
  size_t oa = ((size_t)img<<16) + (size_t)p;
  out[O_ATTN + oa] = attn;
  out[O_OMA  + oa] = na;
}

// ---------------- launch ----------------
extern "C" void kernel_launch(void* const* d_in, const int* in_sizes, int n_in,
                              void* d_out, int out_size, void* d_ws, size_t ws_size,
                              hipStream_t stream){
  (void)in_sizes; (void)n_in; (void)out_size; (void)ws_size;
  char* ws = (char*)d_ws;
  float* h   = (float*)(ws + WS_H);
  u16*  tH   = (u16*)(ws + WS_TH);
  u16*  tL   = (u16*)(ws + WS_TL);
  u16*  wdH  = (u16*)(ws + WS_WDH);
  u16*  wdL  = (u16*)(ws + WS_WDL);
  u16*  w2H  = (u16*)(ws + WS_W2H);
  u16*  w2L  = (u16*)(ws + WS_W2L);
  float* w0t = (float*)(ws + WS_W0T);
  u16*  wfH  = (u16*)(ws + WS_WFH);
  u16*  wfL  = (u16*)(ws + WS_WFL);
  float* par = (float*)(ws + WS_PAR);
  float* out = (float*)d_out;

  k_prep<<<1,256,0,stream>>>((const float*)d_in[4],(const float*)d_in[5],(const float*)d_in[6],(const float*)d_in[7],
                             (const float*)d_in[9],(const float*)d_in[10],(const float*)d_in[11],(const float*)d_in[12],
                             (const float*)d_in[15],(const float*)d_in[16],(const float*)d_in[17],(const float*)d_in[18],
                             (const float*)d_in[20],(const float*)d_in[21],(const float*)d_in[22],(const float*)d_in[23],
                             (const float*)d_in[3],(const float*)d_in[25], par);
  k_wx2<<<14,256,0,stream>>>((const float*)d_in[8], w0t);
  k_wxm<<<4392,256,0,stream>>>((const float*)d_in[13],(const float*)d_in[14],(const float*)d_in[19],
                               (const float*)d_in[24],
                               wdH, wdL, w2H, w2L, wfH, wfL);

  dim3 g0(16,32,4);   // conv0: 16x8 tiles
  dim3 gm(8,32,4);    // mfma convs: 32x8 tiles
  for (int dir=0; dir<2; dir++){
    const float* im = (const float*)d_in[dir];
    float* dmask = out + (dir ? O_MASKB : O_MASKF);
    k_conv0<<<g0,256,0,stream>>>(im, h, w0t, par+S0, par+T0);
    for (int b=0;b<10;b++){
      // dual conv: h --bn1+relu--> conv(18 taps) --bn2+relu+split--> tH/tL
      k_mc<18,0,3,2,0><<<gm,256,0,stream>>>(h, nullptr, nullptr, tH, tL,
          wdH + (size_t)b*73728, wdL + (size_t)b*73728,
          par + S1 + b*64, par + T1 + b*64,
          par + S2 + b*64, par + T2 + b*64, nullptr, nullptr);
      // w2 conv: tH/tL (pre-activated) --conv(9 taps)--> h += (residual)
      k_mc<9,1,1,2,1><<<gm,256,0,stream>>>(tH, tL, h, nullptr, nullptr,
          w2H + (size_t)b*36864, w2L + (size_t)b*36864,
          nullptr, nullptr, nullptr, nullptr, nullptr, nullptr);
    }
    // fin: h --bnf+relu--> conv(9 taps) + bias --softmax25--> dmask
    k_mc<9,1,2,1,0><<<gm,256,0,stream>>>(h, nullptr, nullptr, nullptr, nullptr,
        wfH, wfL, par + SF, par + TF, nullptr, nullptr, par + CB, dmask);
  }
  k_blend<<<1024,256,0,stream>>>(out, (const float*)d_in[0], (const float*)d_in[1],
                                 (const float*)d_in[2], par, out);
}